// Round 15
// baseline (847.670 us; speedup 1.0000x reference)
//
#include <hip/hip_runtime.h>
#include <hip/hip_bf16.h>

typedef __bf16 bf16x8 __attribute__((ext_vector_type(8)));
typedef float  f32x4  __attribute__((ext_vector_type(4)));
typedef unsigned short u16;

#define T_N 512
#define H_N 256
#define B_N 4
#define V_N 8192
#define E_N 64

__device__ __forceinline__ float tanh_fast(float x) {
    float e = __expf(2.0f * x);
    return 1.0f - __fdividef(2.0f, e + 1.0f);
}

// Pade(5,4) tanh: err <1e-4 for |x|<=3 (args are small here); 1 trans op.
__device__ __forceinline__ float tanh_pade(float x) {
    x = fminf(3.0f, fmaxf(-3.0f, x));
    float x2 = x * x;
    float num = x * (945.0f + x2 * (105.0f + x2));
    float den = 945.0f + x2 * (420.0f + 15.0f * x2);
    return num * __frcp_rn(den);
}

__device__ __forceinline__ u16 f2bf(float f) {
    __hip_bfloat16 h = __float2bfloat16(f);   // RTNE
    return __builtin_bit_cast(u16, h);
}

__device__ __forceinline__ bf16x8 as_bf16x8(uint4 u) {
    return __builtin_bit_cast(bf16x8, u);
}

__device__ __forceinline__ uint4 pack_bf8(f32x4 lo, f32x4 hi) {
    union { u16 s[8]; uint4 u; } r;
    #pragma unroll
    for (int e = 0; e < 4; ++e) { r.s[e] = f2bf(lo[e]); r.s[e+4] = f2bf(hi[e]); }
    return r.u;
}

__device__ __forceinline__ f32x4 mfma16(bf16x8 a, bf16x8 b, f32x4 c) {
    return __builtin_amdgcn_mfma_f32_16x16x32_bf16(a, b, c, 0, 0, 0);
}

// async global->LDS, 16B per lane; lds base must be wave-uniform
__device__ __forceinline__ void gload_lds16(const u16* g, u16* l) {
    __builtin_amdgcn_global_load_lds(
        (const __attribute__((address_space(1))) unsigned int*)g,
        (__attribute__((address_space(3))) unsigned int*)l, 16, 0, 0);
}

// ---------------------------------------------------------------------------
__global__ void cvt_bf16_kernel(const float* __restrict__ src, u16* __restrict__ dst, int n4) {
    int i = blockIdx.x * 256 + threadIdx.x;
    if (i < n4) {
        f32x4 v = ((const f32x4*)src)[i];
        union { u16 s[4]; unsigned long long u; } r;
        #pragma unroll
        for (int e = 0; e < 4; ++e) r.s[e] = f2bf(v[e]);
        ((unsigned long long*)dst)[i] = r.u;
    }
}

// ---------------------------------------------------------------------------
// Pre-pack Wih1 (256x256 f32) into MFMA B-fragments in GLOBAL, frag order:
// out[((jt*8 + kk)*64 + lane)] = 8 bf16 of Wih1[jt*16 + (lane&15)][kk*32 + (lane>>4)*8 ..+7]
__global__ __launch_bounds__(256)
void prep_wih1_kernel(const float* __restrict__ Wih1, uint4* __restrict__ out) {
    const int f = blockIdx.x * 256 + threadIdx.x;   // 0 .. 8191
    const int jt = f >> 9, kk = (f >> 6) & 7, lo = f & 63;
    const int mo = lo & 15, go = lo >> 4;
    const float* p = Wih1 + (size_t)(jt * 16 + mo) * H_N + (kk << 5) + (go << 3);
    f32x4 a = *(const f32x4*)p;
    f32x4 b = *(const f32x4*)(p + 4);
    out[f] = pack_bf8(a, b);
}

// ---------------------------------------------------------------------------
// embedding gather + xW0 = e @ W_ih0^T + b_ih0 + b_hh0, stored [t][j][b] f32
__global__ __launch_bounds__(256)
void embed_xw0_kernel(const int* __restrict__ x, const float* __restrict__ emb,
                      const float* __restrict__ Wih, const float* __restrict__ bih,
                      const float* __restrict__ bhh, float* __restrict__ xw0) {
    const int t = blockIdx.x, tid = threadIdx.x;
    __shared__ float sE[4][64];
    {
        const int b = tid >> 6, k = tid & 63;
        sE[b][k] = emb[(size_t)x[b * T_N + t] * E_N + k];
    }
    __syncthreads();
    const int j = tid;
    const float* wr = Wih + j * E_N;
    float a0 = 0, a1 = 0, a2 = 0, a3 = 0;
    #pragma unroll 8
    for (int k = 0; k < E_N; ++k) {
        float wv = wr[k];
        a0 += sE[0][k] * wv; a1 += sE[1][k] * wv;
        a2 += sE[2][k] * wv; a3 += sE[3][k] * wv;
    }
    const float bs = bih[j] + bhh[j];
    f32x4 o = { a0 + bs, a1 + bs, a2 + bs, a3 + bs };
    *(f32x4*)(xw0 + ((size_t)t * H_N + j) * 4) = o;
}

// ---------------------------------------------------------------------------
// FUSED 2-layer tanh-RNN, ONE workgroup, 8 waves. R8-EXACT (660us verified;
// R9/R10/R11 restructurings all regressed via register-pressure cliffs —
// this loop body tolerates NO added register state). FROZEN.
__global__ __launch_bounds__(512, 2)
void rnn_fused_kernel(const float* __restrict__ Whh0, const float* __restrict__ Whh1,
                      const uint4* __restrict__ xfg, const float* __restrict__ bih1,
                      const float* __restrict__ bhh1, const float* __restrict__ xw0,
                      u16* __restrict__ y1bf, float* __restrict__ y1f,
                      float* __restrict__ hT) {
    __shared__ __align__(16) u16   ring[8][4][288];    // y0 bf16 ring, 18.4KB
    __shared__ __align__(16) u16   h1b[2][4][288];     // h1 dbuf, 4.6KB
    __shared__ __align__(16) float xwb[2][4][256][4];  // xw1 blocks f32, 32KB

    const int tid = threadIdx.x;
    const int w = tid >> 6, l = tid & 63;
    const int m = l & 15, g = l >> 4, b4 = m & 3;
    const int layer = w >> 2, wl = w & 3;
    const int jmy = (wl << 6) + l;

    for (int i = tid; i < 8 * 4 * 288; i += 512) (&ring[0][0][0])[i] = (u16)0;
    for (int i = tid; i < 2 * 4 * 288; i += 512) (&h1b[0][0][0])[i] = (u16)0;

    // W_hh B-frags in registers (layer-specific)
    const float* Whh = (layer == 0) ? Whh0 : Whh1;
    bf16x8 wfrag[4][8];
    #pragma unroll
    for (int nt = 0; nt < 4; ++nt) {
        const int j = (wl << 6) + (nt << 4) + m;
        #pragma unroll
        for (int kk = 0; kk < 8; ++kk) {
            const float* p = Whh + (size_t)j * H_N + (kk << 5) + (g << 3);
            f32x4 lo4 = *(const f32x4*)p;
            f32x4 hi4 = *(const f32x4*)(p + 4);
            wfrag[nt][kk] = as_bf16x8(pack_bf8(lo4, hi4));
        }
    }

    const float bias1 = bih1[jmy] + bhh1[jmy];
    const f32x4* xwv = (const f32x4*)xw0;
    f32x4 xw_cur = xwv[jmy];                    // xw0[t=0] (L0 uses)
    const uint4* xgw = xfg + ((size_t)w << 10); // this wave's 32-feature slice

    __syncthreads();

    for (int it = 0; it < 517; ++it) {
        const bool burst = ((it & 3) == 0) && (it >= 4) && (it <= 512);

        // pre-issue first half (tile 0) of Wih1 frag loads: latency hides under chain
        uint4 xf0[8];
        if (burst) {
            #pragma unroll
            for (int kk = 0; kk < 8; ++kk) xf0[kk] = xgw[(kk << 6) + l];
        }

        if (layer == 0) {
            if (it < 512) {
                const int tn = (it + 1 < 512) ? it + 1 : it;
                f32x4 xw_nxt = xwv[(size_t)tn * H_N + jmy];
                const int rs = (it - 1) & 7;

                bf16x8 af[8];
                #pragma unroll
                for (int kk = 0; kk < 8; ++kk)
                    af[kk] = as_bf16x8(*(const uint4*)&ring[rs][b4][(kk << 5) + (g << 3)]);

                f32x4 ca[4], cb[4];
                #pragma unroll
                for (int nt = 0; nt < 4; ++nt) {
                    ca[nt] = (f32x4){0.f, 0.f, 0.f, 0.f};
                    cb[nt] = (f32x4){0.f, 0.f, 0.f, 0.f};
                }
                #pragma unroll
                for (int kk = 0; kk < 4; ++kk)
                    #pragma unroll
                    for (int nt = 0; nt < 4; ++nt) {
                        ca[nt] = mfma16(af[kk],     wfrag[nt][kk],     ca[nt]);
                        cb[nt] = mfma16(af[kk + 4], wfrag[nt][kk + 4], cb[nt]);
                    }

                f32x4 hv = (g == 0) ? (ca[0] + cb[0])
                         : (g == 1) ? (ca[1] + cb[1])
                         : (g == 2) ? (ca[2] + cb[2])
                         :            (ca[3] + cb[3]);
                hv += xw_cur;

                #pragma unroll
                for (int b = 0; b < 4; ++b) {
                    float hn = tanh_fast(hv[b]);
                    ring[it & 7][b][jmy] = f2bf(hn);
                    if (it == T_N - 1) hT[b * H_N + jmy] = hn;   // h0 final
                }
                xw_cur = xw_nxt;
            }
        } else {
            if (it >= 5) {
                const int s = it - 5;
                f32x4 xws = *(const f32x4*)&xwb[(s >> 2) & 1][s & 3][jmy][0];
                const int rs = (s - 1) & 1;

                bf16x8 af[8];
                #pragma unroll
                for (int kk = 0; kk < 8; ++kk)
                    af[kk] = as_bf16x8(*(const uint4*)&h1b[rs][b4][(kk << 5) + (g << 3)]);

                f32x4 ca[4], cb[4];
                #pragma unroll
                for (int nt = 0; nt < 4; ++nt) {
                    ca[nt] = (f32x4){0.f, 0.f, 0.f, 0.f};
                    cb[nt] = (f32x4){0.f, 0.f, 0.f, 0.f};
                }
                #pragma unroll
                for (int kk = 0; kk < 4; ++kk)
                    #pragma unroll
                    for (int nt = 0; nt < 4; ++nt) {
                        ca[nt] = mfma16(af[kk],     wfrag[nt][kk],     ca[nt]);
                        cb[nt] = mfma16(af[kk + 4], wfrag[nt][kk + 4], cb[nt]);
                    }

                f32x4 hv = (g == 0) ? (ca[0] + cb[0])
                         : (g == 1) ? (ca[1] + cb[1])
                         : (g == 2) ? (ca[2] + cb[2])
                         :            (ca[3] + cb[3]);
                hv += xws;
                hv += (f32x4){bias1, bias1, bias1, bias1};

                #pragma unroll
                for (int b = 0; b < 4; ++b) {
                    float hn = tanh_fast(hv[b]);
                    u16 bits = f2bf(hn);
                    h1b[s & 1][b][jmy] = bits;
                    y1bf[((size_t)b * T_N + s) * H_N + jmy] = bits;
                    y1f [((size_t)b * T_N + s) * H_N + jmy] = hn;
                    if (s == T_N - 1) hT[1024 + b * H_N + jmy] = hn;  // h1 final
                }
            }
        }

        if (burst) {
            const int t0 = it - 4;
            const int par = ((it - 4) >> 2) & 1;
            // A-frags: row r=m -> (t = t0 + (m>>2), b = m&3); full 16 rows used
            const int slotm = (t0 + (m >> 2)) & 7;
            bf16x8 ax[8];
            #pragma unroll
            for (int kk = 0; kk < 8; ++kk)
                ax[kk] = as_bf16x8(*(const uint4*)&ring[slotm][b4][(kk << 5) + (g << 3)]);

            f32x4 xa0 = {0.f, 0.f, 0.f, 0.f};
            #pragma unroll
            for (int kk = 0; kk < 8; ++kk)
                xa0 = mfma16(ax[kk], as_bf16x8(xf0[kk]), xa0);

            uint4 xf1[8];
            #pragma unroll
            for (int kk = 0; kk < 8; ++kk) xf1[kk] = xgw[512 + (kk << 6) + l];

            f32x4 xa1 = {0.f, 0.f, 0.f, 0.f};
            #pragma unroll
            for (int kk = 0; kk < 8; ++kk)
                xa1 = mfma16(ax[kk], as_bf16x8(xf1[kk]), xa1);

            // lane (m,g): C rows 4g+r -> t = t0+g, b = r; cols = feats
            *(f32x4*)&xwb[par][g][(w << 5) + m][0]      = xa0;
            *(f32x4*)&xwb[par][g][(w << 5) + 16 + m][0] = xa1;
        }

        // LDS-only barrier: h/xw writes visible; global ops stay in flight
        asm volatile("s_waitcnt lgkmcnt(0)\n\ts_barrier" ::: "memory");
    }
}

// ---------------------------------------------------------------------------
// FUSED q/k GEMM: blocks 0-127 compute q = y1 @ Wq^T (f32 [row][256]);
// blocks 128-255 compute kT = (y1 @ Wk^T) transposed to [b][256][512].
__global__ __launch_bounds__(256, 2)
void gemm_qk_kernel(const u16* __restrict__ A, const u16* __restrict__ Wqb,
                    const u16* __restrict__ Wkb, float* __restrict__ qf,
                    float* __restrict__ kTo) {
    __shared__ __align__(16) u16 As[64][40];
    __shared__ __align__(16) u16 Bs[64][40];
    const int tid = threadIdx.x;
    const bool isQ = blockIdx.x < 128;
    const int blk = isQ ? blockIdx.x : blockIdx.x - 128;
    const u16* Bw = isQ ? Wqb : Wkb;
    constexpr int K = 256, N = 256;
    const int bm = blk >> 2, bn = blk & 3;
    const int l = tid & 63, w = tid >> 6;
    const int wm = w & 1, wn = w >> 1;
    const int m = l & 15, g = l >> 4;
    const int srow = tid >> 2, sseg = tid & 3;

    f32x4 c[2][2];
    #pragma unroll
    for (int i = 0; i < 2; ++i)
        #pragma unroll
        for (int j = 0; j < 2; ++j) c[i][j] = (f32x4){0.f, 0.f, 0.f, 0.f};

    const u16* ap = A  + (size_t)(bm * 64 + srow) * K + sseg * 8;
    const u16* bp = Bw + (size_t)(bn * 64 + srow) * K + sseg * 8;

    for (int k0 = 0; k0 < K; k0 += 32) {
        uint4 av = *(const uint4*)(ap + k0);
        uint4 bv = *(const uint4*)(bp + k0);
        __syncthreads();
        *(uint4*)&As[srow][sseg << 3] = av;
        *(uint4*)&Bs[srow][sseg << 3] = bv;
        __syncthreads();
        bf16x8 af[2], bfr[2];
        #pragma unroll
        for (int i = 0; i < 2; ++i) {
            af[i]  = as_bf16x8(*(const uint4*)&As[(wm << 5) + (i << 4) + m][g << 3]);
            bfr[i] = as_bf16x8(*(const uint4*)&Bs[(wn << 5) + (i << 4) + m][g << 3]);
        }
        #pragma unroll
        for (int i = 0; i < 2; ++i)
            #pragma unroll
            for (int j = 0; j < 2; ++j)
                c[i][j] = mfma16(af[i], bfr[j], c[i][j]);
    }

    #pragma unroll
    for (int i = 0; i < 2; ++i)
        #pragma unroll
        for (int j = 0; j < 2; ++j) {
            const int col = (bn << 6) + (wn << 5) + (j << 4) + m;
            #pragma unroll
            for (int r = 0; r < 4; ++r) {
                const int row = (bm << 6) + (wm << 5) + (i << 4) + (g << 2) + r;
                const float val = c[i][j][r];
                if (isQ) {
                    qf[(size_t)row * N + col] = val;
                } else {
                    const int b = row >> 9, t = row & 511;
                    kTo[(size_t)b * N * T_N + (size_t)col * T_N + t] = val;
                }
            }
        }
}

// ---------------------------------------------------------------------------
// FC GEMM: out(2048x8192) = A(2048x512,bf16) @ Wfc(8192x512,bf16)^T + bfc
// R14: m97-style staging — async global_load_lds width-16 into LINEAR LDS
// [row][32] (64B rows). Per k-step each thread issues 2 A + 2 B loads
// (wave-uniform LDS base (w*2+q)*1KB, per-lane global src); __syncthreads
// drains vmcnt. Read-side linear frags (~8-way alias, m97-proven net win);
// staging VALU/addr work and the write-side swizzle are gone.
__global__ __launch_bounds__(256, 2)
void gemm_fc(const u16* __restrict__ A, const u16* __restrict__ Bw,
             const float* __restrict__ bias, float* __restrict__ out) {
    __shared__ __align__(16) u16 As[128 * 32];
    __shared__ __align__(16) u16 Bs[128 * 32];
    const int tid = threadIdx.x;
    const int l = tid & 63, w = tid >> 6;
    const int m = l & 15, g = l >> 4;
    const int wm = w >> 1, wn = w & 1;
    const int bm = blockIdx.x >> 6, bn = blockIdx.x & 63;
    constexpr int K = 512;

    f32x4 acc[4][4];
    #pragma unroll
    for (int i = 0; i < 4; ++i)
        #pragma unroll
        for (int j = 0; j < 4; ++j) acc[i][j] = (f32x4){0.f, 0.f, 0.f, 0.f};

    const u16* aBase = A  + (size_t)(bm * 128) * K;
    const u16* bBase = Bw + (size_t)(bn * 128) * K;
    // chunk c = (w*2+q)*64 + l -> row = c>>2, seg = c&3; LDS byte = c*16 (linear)
    const int c0r = ((w << 1) + 0) * 64 + l;
    const int c1r = ((w << 1) + 1) * 64 + l;
    const int rowA0 = c0r >> 2, segA0 = c0r & 3;
    const int rowA1 = c1r >> 2, segA1 = c1r & 3;
    u16* ldsA0 = As + ((w << 1) + 0) * 512;   // u16 units: 1KB = 512 u16
    u16* ldsA1 = As + ((w << 1) + 1) * 512;
    u16* ldsB0 = Bs + ((w << 1) + 0) * 512;
    u16* ldsB1 = Bs + ((w << 1) + 1) * 512;

    for (int k0 = 0; k0 < K; k0 += 32) {
        __syncthreads();   // previous tile's reads complete before overwrite
        gload_lds16(aBase + (size_t)rowA0 * K + k0 + segA0 * 8, ldsA0);
        gload_lds16(aBase + (size_t)rowA1 * K + k0 + segA1 * 8, ldsA1);
        gload_lds16(bBase + (size_t)rowA0 * K + k0 + segA0 * 8, ldsB0);
        gload_lds16(bBase + (size_t)rowA1 * K + k0 + segA1 * 8, ldsB1);
        __syncthreads();   // drains vmcnt(0): LDS data visible

        bf16x8 af[4], bfr[4];
        #pragma unroll
        for (int i = 0; i < 4; ++i) {
            const int arow = wm * 64 + i * 16 + m;
            af[i]  = as_bf16x8(*(const uint4*)(As + arow * 32 + g * 8));
            const int brow = wn * 64 + i * 16 + m;
            bfr[i] = as_bf16x8(*(const uint4*)(Bs + brow * 32 + g * 8));
        }
        #pragma unroll
        for (int i = 0; i < 4; ++i)
            #pragma unroll
            for (int j = 0; j < 4; ++j)
                acc[i][j] = mfma16(af[i], bfr[j], acc[i][j]);
    }

    #pragma unroll
    for (int i = 0; i < 4; ++i)
        #pragma unroll
        for (int j = 0; j < 4; ++j) {
            const int col = bn * 128 + wn * 64 + j * 16 + m;
            const float bs = bias[col];
            #pragma unroll
            for (int r = 0; r < 4; ++r) {
                const int row = bm * 128 + wm * 64 + i * 16 + (g << 2) + r;
                out[(size_t)row * V_N + col] = acc[i][j][r] + bs;
            }
        }
}

// ---------------------------------------------------------------------------
// Bahdanau attention + FUSED LayerNorm, one block per (b, i). (R13-verified)
__global__ __launch_bounds__(256)
void attn_ln_kernel(const float* __restrict__ q, const float* __restrict__ kT,
                    const float* __restrict__ y1f, const float* __restrict__ vvec,
                    const float* __restrict__ gamma, const float* __restrict__ beta,
                    u16* __restrict__ outbf) {
    const int blk = blockIdx.x;
    const int b = blk >> 9, i = blk & 511;
    const int tid = threadIdx.x;
    __shared__ float sQ[H_N], sV[H_N], sS[T_N];
    __shared__ float red[4];
    sQ[tid] = q[((size_t)b * T_N + i) * H_N + tid];
    sV[tid] = vvec[tid];
    __syncthreads();

    float s0 = -1e30f, s1 = -1e30f;
    if (tid <= i) {
        const float* kp = kT + (size_t)b * H_N * T_N + tid;
        float acc = 0.f;
        for (int h = 0; h < H_N; ++h) acc += sV[h] * tanh_pade(sQ[h] + kp[(size_t)h * T_N]);
        s0 = acc;
    }
    if (tid + 256 <= i) {
        const float* kp = kT + (size_t)b * H_N * T_N + tid + 256;
        float acc = 0.f;
        for (int h = 0; h < H_N; ++h) acc += sV[h] * tanh_pade(sQ[h] + kp[(size_t)h * T_N]);
        s1 = acc;
    }
    float mv = fmaxf(s0, s1);
    #pragma unroll
    for (int o = 32; o; o >>= 1) mv = fmaxf(mv, __shfl_xor(mv, o, 64));
    if ((tid & 63) == 0) red[tid >> 6] = mv;
    __syncthreads();
    mv = fmaxf(fmaxf(red[0], red[1]), fmaxf(red[2], red[3]));
    __syncthreads();
    float e0 = (tid <= i)       ? __expf(s0 - mv) : 0.f;
    float e1 = (tid + 256 <= i) ? __expf(s1 - mv) : 0.f;
    float sm = e0 + e1;
    #pragma unroll
    for (int o = 32; o; o >>= 1) sm += __shfl_xor(sm, o, 64);
    if ((tid & 63) == 0) red[tid >> 6] = sm;
    __syncthreads();
    sm = red[0] + red[1] + red[2] + red[3];
    const float rs = 1.0f / sm;
    sS[tid] = e0 * rs;
    sS[tid + 256] = e1 * rs;
    __syncthreads();
    float acc = 0.f;
    const float* yp = y1f + (size_t)b * T_N * H_N + tid;
    for (int j2 = 0; j2 <= i; ++j2) acc += sS[j2] * yp[(size_t)j2 * H_N];

    // ---- fused LayerNorm over cat([y1 row, ctx row]) (512 elems) ----
    const float x1 = y1f[((size_t)b * T_N + i) * H_N + tid];
    const float x2 = acc;
    float s = x1 + x2;
    #pragma unroll
    for (int o = 32; o; o >>= 1) s += __shfl_xor(s, o, 64);
    if ((tid & 63) == 0) red[tid >> 6] = s;
    __syncthreads();
    const float mu = (red[0] + red[1] + red[2] + red[3]) * (1.f / 512.f);
    __syncthreads();
    const float d1 = x1 - mu, d2 = x2 - mu;
    float qv = d1 * d1 + d2 * d2;
    #pragma unroll
    for (int o = 32; o; o >>= 1) qv += __shfl_xor(qv, o, 64);
    if ((tid & 63) == 0) red[tid >> 6] = qv;
    __syncthreads();
    const float var = (red[0] + red[1] + red[2] + red[3]) * (1.f / 512.f);
    const float inv = rsqrtf(var + 1e-5f);
    const size_t row = (size_t)b * T_N + i;
    outbf[row * 512 + tid]       = f2bf(d1 * inv * gamma[tid] + beta[tid]);
    outbf[row * 512 + tid + 256] = f2bf(d2 * inv * gamma[tid + 256] + beta[tid + 256]);
}

// ---------------------------------------------------------------------------
extern "C" void kernel_launch(void* const* d_in, const int* in_sizes, int n_in,
                              void* d_out, int out_size, void* d_ws, size_t ws_size,
                              hipStream_t stream) {
    const int*   x     = (const int*)  d_in[0];
    const float* emb   = (const float*)d_in[1];
    const float* Wih0  = (const float*)d_in[2];
    const float* Whh0  = (const float*)d_in[3];
    const float* bih0  = (const float*)d_in[4];
    const float* bhh0  = (const float*)d_in[5];
    const float* Wih1  = (const float*)d_in[6];
    const float* Whh1  = (const float*)d_in[7];
    const float* bih1  = (const float*)d_in[8];
    const float* bhh1  = (const float*)d_in[9];
    const float* Wq    = (const float*)d_in[10];
    const float* Wk    = (const float*)d_in[11];
    const float* vvec  = (const float*)d_in[12];
    const float* gamma = (const float*)d_in[13];
    const float* beta  = (const float*)d_in[14];
    const float* Wfc   = (const float*)d_in[15];
    const float* bfc   = (const float*)d_in[16];

    float* outp = (float*)d_out;
    char* ws = (char*)d_ws;
    float* xw0   = (float*)(ws + 0);         // 2MB  [T][H][B]
    uint4* xfg   = (uint4*)(ws + 2097152);   // 128KB pre-packed Wih1 frags
    u16*   y1bf  = (u16*)  (ws + 5242880);   // 1MB  [B][T][H]
    float* y1f   = (float*)(ws + 6291456);   // 2MB  [B][T][H]
    float* qf    = (float*)(ws + 8388608);   // 2MB  [B][T][H]
    float* kT    = (float*)(ws + 10485760);  // 2MB  [B][H][T]
    u16*   nrm   = (u16*)  (ws + 14680064);  // 2MB  [B*T][512]
    u16*   Wqb   = (u16*)  (ws + 16908288);
    u16*   Wkb   = (u16*)  (ws + 17039360);
    u16*   Wfcb  = (u16*)  (ws + 17170432);  // 8MB

    float* hout = outp + (size_t)B_N * T_N * V_N;

    cvt_bf16_kernel<<<64,   256, 0, stream>>>(Wq,  Wqb,  65536 / 4);
    cvt_bf16_kernel<<<64,   256, 0, stream>>>(Wk,  Wkb,  65536 / 4);
    cvt_bf16_kernel<<<4096, 256, 0, stream>>>(Wfc, Wfcb, 4194304 / 4);
    prep_wih1_kernel<<<32, 256, 0, stream>>>(Wih1, xfg);

    embed_xw0_kernel<<<512, 256, 0, stream>>>(x, emb, Wih0, bih0, bhh0, xw0);
    rnn_fused_kernel<<<1, 512, 0, stream>>>(Whh0, Whh1, xfg, bih1, bhh1,
                                            xw0, y1bf, y1f, hout);
    gemm_qk_kernel<<<256, 256, 0, stream>>>(y1bf, Wqb, Wkb, qf, kT);
    attn_ln_kernel<<<2048, 256, 0, stream>>>(qf, kT, y1f, vvec, gamma, beta, nrm);
    gemm_fc<<<16 * 64, 256, 0, stream>>>(nrm, Wfcb, bfc, outp);
}

// Round 16
// 840.461 us; speedup vs baseline: 1.0086x; 1.0086x over previous
//
#include <hip/hip_runtime.h>
#include <hip/hip_bf16.h>

typedef __bf16 bf16x8 __attribute__((ext_vector_type(8)));
typedef float  f32x4  __attribute__((ext_vector_type(4)));
typedef unsigned short u16;

#define T_N 512
#define H_N 256
#define B_N 4
#define V_N 8192
#define E_N 64

__device__ __forceinline__ float tanh_fast(float x) {
    float e = __expf(2.0f * x);
    return 1.0f - __fdividef(2.0f, e + 1.0f);
}

// Pade(5,4) tanh: err <1e-4 for |x|<=3 (args are small here); 1 trans op.
__device__ __forceinline__ float tanh_pade(float x) {
    x = fminf(3.0f, fmaxf(-3.0f, x));
    float x2 = x * x;
    float num = x * (945.0f + x2 * (105.0f + x2));
    float den = 945.0f + x2 * (420.0f + 15.0f * x2);
    return num * __frcp_rn(den);
}

__device__ __forceinline__ u16 f2bf(float f) {
    __hip_bfloat16 h = __float2bfloat16(f);   // RTNE
    return __builtin_bit_cast(u16, h);
}

__device__ __forceinline__ bf16x8 as_bf16x8(uint4 u) {
    return __builtin_bit_cast(bf16x8, u);
}

__device__ __forceinline__ uint4 pack_bf8(f32x4 lo, f32x4 hi) {
    union { u16 s[8]; uint4 u; } r;
    #pragma unroll
    for (int e = 0; e < 4; ++e) { r.s[e] = f2bf(lo[e]); r.s[e+4] = f2bf(hi[e]); }
    return r.u;
}

__device__ __forceinline__ f32x4 mfma16(bf16x8 a, bf16x8 b, f32x4 c) {
    return __builtin_amdgcn_mfma_f32_16x16x32_bf16(a, b, c, 0, 0, 0);
}

// async global->LDS, 16B per lane; lds base must be wave-uniform
__device__ __forceinline__ void gload_lds16(const u16* g, u16* l) {
    __builtin_amdgcn_global_load_lds(
        (const __attribute__((address_space(1))) unsigned int*)g,
        (__attribute__((address_space(3))) unsigned int*)l, 16, 0, 0);
}

// ---------------------------------------------------------------------------
// MERGED weight-prep kernel (R15): one launch does all four independent jobs
// (was 3x cvt + 1x prep_wih1 serialized in graph order).
//   blocks 0..63     : Wq  -> bf16
//   blocks 64..127   : Wk  -> bf16
//   blocks 128..4223 : Wfc -> bf16
//   blocks 4224..4255: Wih1 -> packed MFMA B-frags
__global__ __launch_bounds__(256)
void prep_all_kernel(const float* __restrict__ Wq,  u16* __restrict__ Wqb,
                     const float* __restrict__ Wk,  u16* __restrict__ Wkb,
                     const float* __restrict__ Wfc, u16* __restrict__ Wfcb,
                     const float* __restrict__ Wih1, uint4* __restrict__ xfg) {
    const int blk = blockIdx.x, tid = threadIdx.x;
    if (blk < 4224) {
        const float* src;
        u16* dst;
        int i;
        if (blk < 64)       { src = Wq;  dst = Wqb;  i = blk * 256 + tid; }
        else if (blk < 128) { src = Wk;  dst = Wkb;  i = (blk - 64) * 256 + tid; }
        else                { src = Wfc; dst = Wfcb; i = (blk - 128) * 256 + tid; }
        f32x4 v = ((const f32x4*)src)[i];
        union { u16 s[4]; unsigned long long u; } r;
        #pragma unroll
        for (int e = 0; e < 4; ++e) r.s[e] = f2bf(v[e]);
        ((unsigned long long*)dst)[i] = r.u;
    } else {
        const int f = (blk - 4224) * 256 + tid;   // 0 .. 8191
        const int jt = f >> 9, kk = (f >> 6) & 7, lo = f & 63;
        const int mo = lo & 15, go = lo >> 4;
        const float* p = Wih1 + (size_t)(jt * 16 + mo) * H_N + (kk << 5) + (go << 3);
        f32x4 a = *(const f32x4*)p;
        f32x4 b = *(const f32x4*)(p + 4);
        xfg[f] = pack_bf8(a, b);
    }
}

// ---------------------------------------------------------------------------
// embedding gather + xW0 = e @ W_ih0^T + b_ih0 + b_hh0, stored [t][j][b] f32
__global__ __launch_bounds__(256)
void embed_xw0_kernel(const int* __restrict__ x, const float* __restrict__ emb,
                      const float* __restrict__ Wih, const float* __restrict__ bih,
                      const float* __restrict__ bhh, float* __restrict__ xw0) {
    const int t = blockIdx.x, tid = threadIdx.x;
    __shared__ float sE[4][64];
    {
        const int b = tid >> 6, k = tid & 63;
        sE[b][k] = emb[(size_t)x[b * T_N + t] * E_N + k];
    }
    __syncthreads();
    const int j = tid;
    const float* wr = Wih + j * E_N;
    float a0 = 0, a1 = 0, a2 = 0, a3 = 0;
    #pragma unroll 8
    for (int k = 0; k < E_N; ++k) {
        float wv = wr[k];
        a0 += sE[0][k] * wv; a1 += sE[1][k] * wv;
        a2 += sE[2][k] * wv; a3 += sE[3][k] * wv;
    }
    const float bs = bih[j] + bhh[j];
    f32x4 o = { a0 + bs, a1 + bs, a2 + bs, a3 + bs };
    *(f32x4*)(xw0 + ((size_t)t * H_N + j) * 4) = o;
}

// ---------------------------------------------------------------------------
// FUSED 2-layer tanh-RNN, ONE workgroup, 8 waves. R8-EXACT (660us verified;
// R9/R10/R11 restructurings all regressed via register-pressure cliffs —
// this loop body tolerates NO added register state). FROZEN.
__global__ __launch_bounds__(512, 2)
void rnn_fused_kernel(const float* __restrict__ Whh0, const float* __restrict__ Whh1,
                      const uint4* __restrict__ xfg, const float* __restrict__ bih1,
                      const float* __restrict__ bhh1, const float* __restrict__ xw0,
                      u16* __restrict__ y1bf, float* __restrict__ y1f,
                      float* __restrict__ hT) {
    __shared__ __align__(16) u16   ring[8][4][288];    // y0 bf16 ring, 18.4KB
    __shared__ __align__(16) u16   h1b[2][4][288];     // h1 dbuf, 4.6KB
    __shared__ __align__(16) float xwb[2][4][256][4];  // xw1 blocks f32, 32KB

    const int tid = threadIdx.x;
    const int w = tid >> 6, l = tid & 63;
    const int m = l & 15, g = l >> 4, b4 = m & 3;
    const int layer = w >> 2, wl = w & 3;
    const int jmy = (wl << 6) + l;

    for (int i = tid; i < 8 * 4 * 288; i += 512) (&ring[0][0][0])[i] = (u16)0;
    for (int i = tid; i < 2 * 4 * 288; i += 512) (&h1b[0][0][0])[i] = (u16)0;

    // W_hh B-frags in registers (layer-specific)
    const float* Whh = (layer == 0) ? Whh0 : Whh1;
    bf16x8 wfrag[4][8];
    #pragma unroll
    for (int nt = 0; nt < 4; ++nt) {
        const int j = (wl << 6) + (nt << 4) + m;
        #pragma unroll
        for (int kk = 0; kk < 8; ++kk) {
            const float* p = Whh + (size_t)j * H_N + (kk << 5) + (g << 3);
            f32x4 lo4 = *(const f32x4*)p;
            f32x4 hi4 = *(const f32x4*)(p + 4);
            wfrag[nt][kk] = as_bf16x8(pack_bf8(lo4, hi4));
        }
    }

    const float bias1 = bih1[jmy] + bhh1[jmy];
    const f32x4* xwv = (const f32x4*)xw0;
    f32x4 xw_cur = xwv[jmy];                    // xw0[t=0] (L0 uses)
    const uint4* xgw = xfg + ((size_t)w << 10); // this wave's 32-feature slice

    __syncthreads();

    for (int it = 0; it < 517; ++it) {
        const bool burst = ((it & 3) == 0) && (it >= 4) && (it <= 512);

        // pre-issue first half (tile 0) of Wih1 frag loads: latency hides under chain
        uint4 xf0[8];
        if (burst) {
            #pragma unroll
            for (int kk = 0; kk < 8; ++kk) xf0[kk] = xgw[(kk << 6) + l];
        }

        if (layer == 0) {
            if (it < 512) {
                const int tn = (it + 1 < 512) ? it + 1 : it;
                f32x4 xw_nxt = xwv[(size_t)tn * H_N + jmy];
                const int rs = (it - 1) & 7;

                bf16x8 af[8];
                #pragma unroll
                for (int kk = 0; kk < 8; ++kk)
                    af[kk] = as_bf16x8(*(const uint4*)&ring[rs][b4][(kk << 5) + (g << 3)]);

                f32x4 ca[4], cb[4];
                #pragma unroll
                for (int nt = 0; nt < 4; ++nt) {
                    ca[nt] = (f32x4){0.f, 0.f, 0.f, 0.f};
                    cb[nt] = (f32x4){0.f, 0.f, 0.f, 0.f};
                }
                #pragma unroll
                for (int kk = 0; kk < 4; ++kk)
                    #pragma unroll
                    for (int nt = 0; nt < 4; ++nt) {
                        ca[nt] = mfma16(af[kk],     wfrag[nt][kk],     ca[nt]);
                        cb[nt] = mfma16(af[kk + 4], wfrag[nt][kk + 4], cb[nt]);
                    }

                f32x4 hv = (g == 0) ? (ca[0] + cb[0])
                         : (g == 1) ? (ca[1] + cb[1])
                         : (g == 2) ? (ca[2] + cb[2])
                         :            (ca[3] + cb[3]);
                hv += xw_cur;

                #pragma unroll
                for (int b = 0; b < 4; ++b) {
                    float hn = tanh_fast(hv[b]);
                    ring[it & 7][b][jmy] = f2bf(hn);
                    if (it == T_N - 1) hT[b * H_N + jmy] = hn;   // h0 final
                }
                xw_cur = xw_nxt;
            }
        } else {
            if (it >= 5) {
                const int s = it - 5;
                f32x4 xws = *(const f32x4*)&xwb[(s >> 2) & 1][s & 3][jmy][0];
                const int rs = (s - 1) & 1;

                bf16x8 af[8];
                #pragma unroll
                for (int kk = 0; kk < 8; ++kk)
                    af[kk] = as_bf16x8(*(const uint4*)&h1b[rs][b4][(kk << 5) + (g << 3)]);

                f32x4 ca[4], cb[4];
                #pragma unroll
                for (int nt = 0; nt < 4; ++nt) {
                    ca[nt] = (f32x4){0.f, 0.f, 0.f, 0.f};
                    cb[nt] = (f32x4){0.f, 0.f, 0.f, 0.f};
                }
                #pragma unroll
                for (int kk = 0; kk < 4; ++kk)
                    #pragma unroll
                    for (int nt = 0; nt < 4; ++nt) {
                        ca[nt] = mfma16(af[kk],     wfrag[nt][kk],     ca[nt]);
                        cb[nt] = mfma16(af[kk + 4], wfrag[nt][kk + 4], cb[nt]);
                    }

                f32x4 hv = (g == 0) ? (ca[0] + cb[0])
                         : (g == 1) ? (ca[1] + cb[1])
                         : (g == 2) ? (ca[2] + cb[2])
                         :            (ca[3] + cb[3]);
                hv += xws;
                hv += (f32x4){bias1, bias1, bias1, bias1};

                #pragma unroll
                for (int b = 0; b < 4; ++b) {
                    float hn = tanh_fast(hv[b]);
                    u16 bits = f2bf(hn);
                    h1b[s & 1][b][jmy] = bits;
                    y1bf[((size_t)b * T_N + s) * H_N + jmy] = bits;
                    y1f [((size_t)b * T_N + s) * H_N + jmy] = hn;
                    if (s == T_N - 1) hT[1024 + b * H_N + jmy] = hn;  // h1 final
                }
            }
        }

        if (burst) {
            const int t0 = it - 4;
            const int par = ((it - 4) >> 2) & 1;
            // A-frags: row r=m -> (t = t0 + (m>>2), b = m&3); full 16 rows used
            const int slotm = (t0 + (m >> 2)) & 7;
            bf16x8 ax[8];
            #pragma unroll
            for (int kk = 0; kk < 8; ++kk)
                ax[kk] = as_bf16x8(*(const uint4*)&ring[slotm][b4][(kk << 5) + (g << 3)]);

            f32x4 xa0 = {0.f, 0.f, 0.f, 0.f};
            #pragma unroll
            for (int kk = 0; kk < 8; ++kk)
                xa0 = mfma16(ax[kk], as_bf16x8(xf0[kk]), xa0);

            uint4 xf1[8];
            #pragma unroll
            for (int kk = 0; kk < 8; ++kk) xf1[kk] = xgw[512 + (kk << 6) + l];

            f32x4 xa1 = {0.f, 0.f, 0.f, 0.f};
            #pragma unroll
            for (int kk = 0; kk < 8; ++kk)
                xa1 = mfma16(ax[kk], as_bf16x8(xf1[kk]), xa1);

            // lane (m,g): C rows 4g+r -> t = t0+g, b = r; cols = feats
            *(f32x4*)&xwb[par][g][(w << 5) + m][0]      = xa0;
            *(f32x4*)&xwb[par][g][(w << 5) + 16 + m][0] = xa1;
        }

        // LDS-only barrier: h/xw writes visible; global ops stay in flight
        asm volatile("s_waitcnt lgkmcnt(0)\n\ts_barrier" ::: "memory");
    }
}

// ---------------------------------------------------------------------------
// FUSED q/k GEMM: blocks 0-127 compute q = y1 @ Wq^T (f32 [row][256]);
// blocks 128-255 compute kT = (y1 @ Wk^T) transposed to [b][256][512].
__global__ __launch_bounds__(256, 2)
void gemm_qk_kernel(const u16* __restrict__ A, const u16* __restrict__ Wqb,
                    const u16* __restrict__ Wkb, float* __restrict__ qf,
                    float* __restrict__ kTo) {
    __shared__ __align__(16) u16 As[64][40];
    __shared__ __align__(16) u16 Bs[64][40];
    const int tid = threadIdx.x;
    const bool isQ = blockIdx.x < 128;
    const int blk = isQ ? blockIdx.x : blockIdx.x - 128;
    const u16* Bw = isQ ? Wqb : Wkb;
    constexpr int K = 256, N = 256;
    const int bm = blk >> 2, bn = blk & 3;
    const int l = tid & 63, w = tid >> 6;
    const int wm = w & 1, wn = w >> 1;
    const int m = l & 15, g = l >> 4;
    const int srow = tid >> 2, sseg = tid & 3;

    f32x4 c[2][2];
    #pragma unroll
    for (int i = 0; i < 2; ++i)
        #pragma unroll
        for (int j = 0; j < 2; ++j) c[i][j] = (f32x4){0.f, 0.f, 0.f, 0.f};

    const u16* ap = A  + (size_t)(bm * 64 + srow) * K + sseg * 8;
    const u16* bp = Bw + (size_t)(bn * 64 + srow) * K + sseg * 8;

    for (int k0 = 0; k0 < K; k0 += 32) {
        uint4 av = *(const uint4*)(ap + k0);
        uint4 bv = *(const uint4*)(bp + k0);
        __syncthreads();
        *(uint4*)&As[srow][sseg << 3] = av;
        *(uint4*)&Bs[srow][sseg << 3] = bv;
        __syncthreads();
        bf16x8 af[2], bfr[2];
        #pragma unroll
        for (int i = 0; i < 2; ++i) {
            af[i]  = as_bf16x8(*(const uint4*)&As[(wm << 5) + (i << 4) + m][g << 3]);
            bfr[i] = as_bf16x8(*(const uint4*)&Bs[(wn << 5) + (i << 4) + m][g << 3]);
        }
        #pragma unroll
        for (int i = 0; i < 2; ++i)
            #pragma unroll
            for (int j = 0; j < 2; ++j)
                c[i][j] = mfma16(af[i], bfr[j], c[i][j]);
    }

    #pragma unroll
    for (int i = 0; i < 2; ++i)
        #pragma unroll
        for (int j = 0; j < 2; ++j) {
            const int col = (bn << 6) + (wn << 5) + (j << 4) + m;
            #pragma unroll
            for (int r = 0; r < 4; ++r) {
                const int row = (bm << 6) + (wm << 5) + (i << 4) + (g << 2) + r;
                const float val = c[i][j][r];
                if (isQ) {
                    qf[(size_t)row * N + col] = val;
                } else {
                    const int b = row >> 9, t = row & 511;
                    kTo[(size_t)b * N * T_N + (size_t)col * T_N + t] = val;
                }
            }
        }
}

// ---------------------------------------------------------------------------
// FC GEMM: out(2048x8192) = A(2048x512,bf16) @ Wfc(8192x512,bf16)^T + bfc
// (R14 gload_lds staging — measured equal to reg-staged; kept, simpler)
__global__ __launch_bounds__(256, 2)
void gemm_fc(const u16* __restrict__ A, const u16* __restrict__ Bw,
             const float* __restrict__ bias, float* __restrict__ out) {
    __shared__ __align__(16) u16 As[128 * 32];
    __shared__ __align__(16) u16 Bs[128 * 32];
    const int tid = threadIdx.x;
    const int l = tid & 63, w = tid >> 6;
    const int m = l & 15, g = l >> 4;
    const int wm = w >> 1, wn = w & 1;
    const int bm = blockIdx.x >> 6, bn = blockIdx.x & 63;
    constexpr int K = 512;

    f32x4 acc[4][4];
    #pragma unroll
    for (int i = 0; i < 4; ++i)
        #pragma unroll
        for (int j = 0; j < 4; ++j) acc[i][j] = (f32x4){0.f, 0.f, 0.f, 0.f};

    const u16* aBase = A  + (size_t)(bm * 128) * K;
    const u16* bBase = Bw + (size_t)(bn * 128) * K;
    const int c0r = ((w << 1) + 0) * 64 + l;
    const int c1r = ((w << 1) + 1) * 64 + l;
    const int rowA0 = c0r >> 2, segA0 = c0r & 3;
    const int rowA1 = c1r >> 2, segA1 = c1r & 3;
    u16* ldsA0 = As + ((w << 1) + 0) * 512;
    u16* ldsA1 = As + ((w << 1) + 1) * 512;
    u16* ldsB0 = Bs + ((w << 1) + 0) * 512;
    u16* ldsB1 = Bs + ((w << 1) + 1) * 512;

    for (int k0 = 0; k0 < K; k0 += 32) {
        __syncthreads();
        gload_lds16(aBase + (size_t)rowA0 * K + k0 + segA0 * 8, ldsA0);
        gload_lds16(aBase + (size_t)rowA1 * K + k0 + segA1 * 8, ldsA1);
        gload_lds16(bBase + (size_t)rowA0 * K + k0 + segA0 * 8, ldsB0);
        gload_lds16(bBase + (size_t)rowA1 * K + k0 + segA1 * 8, ldsB1);
        __syncthreads();

        bf16x8 af[4], bfr[4];
        #pragma unroll
        for (int i = 0; i < 4; ++i) {
            const int arow = wm * 64 + i * 16 + m;
            af[i]  = as_bf16x8(*(const uint4*)(As + arow * 32 + g * 8));
            const int brow = wn * 64 + i * 16 + m;
            bfr[i] = as_bf16x8(*(const uint4*)(Bs + brow * 32 + g * 8));
        }
        #pragma unroll
        for (int i = 0; i < 4; ++i)
            #pragma unroll
            for (int j = 0; j < 4; ++j)
                acc[i][j] = mfma16(af[i], bfr[j], acc[i][j]);
    }

    #pragma unroll
    for (int i = 0; i < 4; ++i)
        #pragma unroll
        for (int j = 0; j < 4; ++j) {
            const int col = bn * 128 + wn * 64 + j * 16 + m;
            const float bs = bias[col];
            #pragma unroll
            for (int r = 0; r < 4; ++r) {
                const int row = bm * 128 + wm * 64 + i * 16 + (g << 2) + r;
                out[(size_t)row * V_N + col] = acc[i][j][r] + bs;
            }
        }
}

// ---------------------------------------------------------------------------
// Bahdanau attention + FUSED LayerNorm, one block per (b, i). (R13-verified)
__global__ __launch_bounds__(256)
void attn_ln_kernel(const float* __restrict__ q, const float* __restrict__ kT,
                    const float* __restrict__ y1f, const float* __restrict__ vvec,
                    const float* __restrict__ gamma, const float* __restrict__ beta,
                    u16* __restrict__ outbf) {
    const int blk = blockIdx.x;
    const int b = blk >> 9, i = blk & 511;
    const int tid = threadIdx.x;
    __shared__ float sQ[H_N], sV[H_N], sS[T_N];
    __shared__ float red[4];
    sQ[tid] = q[((size_t)b * T_N + i) * H_N + tid];
    sV[tid] = vvec[tid];
    __syncthreads();

    float s0 = -1e30f, s1 = -1e30f;
    if (tid <= i) {
        const float* kp = kT + (size_t)b * H_N * T_N + tid;
        float acc = 0.f;
        for (int h = 0; h < H_N; ++h) acc += sV[h] * tanh_pade(sQ[h] + kp[(size_t)h * T_N]);
        s0 = acc;
    }
    if (tid + 256 <= i) {
        const float* kp = kT + (size_t)b * H_N * T_N + tid + 256;
        float acc = 0.f;
        for (int h = 0; h < H_N; ++h) acc += sV[h] * tanh_pade(sQ[h] + kp[(size_t)h * T_N]);
        s1 = acc;
    }
    float mv = fmaxf(s0, s1);
    #pragma unroll
    for (int o = 32; o; o >>= 1) mv = fmaxf(mv, __shfl_xor(mv, o, 64));
    if ((tid & 63) == 0) red[tid >> 6] = mv;
    __syncthreads();
    mv = fmaxf(fmaxf(red[0], red[1]), fmaxf(red[2], red[3]));
    __syncthreads();
    float e0 = (tid <= i)       ? __expf(s0 - mv) : 0.f;
    float e1 = (tid + 256 <= i) ? __expf(s1 - mv) : 0.f;
    float sm = e0 + e1;
    #pragma unroll
    for (int o = 32; o; o >>= 1) sm += __shfl_xor(sm, o, 64);
    if ((tid & 63) == 0) red[tid >> 6] = sm;
    __syncthreads();
    sm = red[0] + red[1] + red[2] + red[3];
    const float rs = 1.0f / sm;
    sS[tid] = e0 * rs;
    sS[tid + 256] = e1 * rs;
    __syncthreads();
    float acc = 0.f;
    const float* yp = y1f + (size_t)b * T_N * H_N + tid;
    for (int j2 = 0; j2 <= i; ++j2) acc += sS[j2] * yp[(size_t)j2 * H_N];

    // ---- fused LayerNorm over cat([y1 row, ctx row]) (512 elems) ----
    const float x1 = y1f[((size_t)b * T_N + i) * H_N + tid];
    const float x2 = acc;
    float s = x1 + x2;
    #pragma unroll
    for (int o = 32; o; o >>= 1) s += __shfl_xor(s, o, 64);
    if ((tid & 63) == 0) red[tid >> 6] = s;
    __syncthreads();
    const float mu = (red[0] + red[1] + red[2] + red[3]) * (1.f / 512.f);
    __syncthreads();
    const float d1 = x1 - mu, d2 = x2 - mu;
    float qv = d1 * d1 + d2 * d2;
    #pragma unroll
    for (int o = 32; o; o >>= 1) qv += __shfl_xor(qv, o, 64);
    if ((tid & 63) == 0) red[tid >> 6] = qv;
    __syncthreads();
    const float var = (red[0] + red[1] + red[2] + red[3]) * (1.f / 512.f);
    const float inv = rsqrtf(var + 1e-5f);
    const size_t row = (size_t)b * T_N + i;
    outbf[row * 512 + tid]       = f2bf(d1 * inv * gamma[tid] + beta[tid]);
    outbf[row * 512 + tid + 256] = f2bf(d2 * inv * gamma[tid + 256] + beta[tid + 256]);
}

// ---------------------------------------------------------------------------
extern "C" void kernel_launch(void* const* d_in, const int* in_sizes, int n_in,
                              void* d_out, int out_size, void* d_ws, size_t ws_size,
                              hipStream_t stream) {
    const int*   x     = (const int*)  d_in[0];
    const float* emb   = (const float*)d_in[1];
    const float* Wih0  = (const float*)d_in[2];
    const float* Whh0  = (const float*)d_in[3];
    const float* bih0  = (const float*)d_in[4];
    const float* bhh0  = (const float*)d_in[5];
    const float* Wih1  = (const float*)d_in[6];
    const float* Whh1  = (const float*)d_in[7];
    const float* bih1  = (const float*)d_in[8];
    const float* bhh1  = (const float*)d_in[9];
    const float* Wq    = (const float*)d_in[10];
    const float* Wk    = (const float*)d_in[11];
    const float* vvec  = (const float*)d_in[12];
    const float* gamma = (const float*)d_in[13];
    const float* beta  = (const float*)d_in[14];
    const float* Wfc   = (const float*)d_in[15];
    const float* bfc   = (const float*)d_in[16];

    float* outp = (float*)d_out;
    char* ws = (char*)d_ws;
    float* xw0   = (float*)(ws + 0);         // 2MB  [T][H][B]
    uint4* xfg   = (uint4*)(ws + 2097152);   // 128KB pre-packed Wih1 frags
    u16*   y1bf  = (u16*)  (ws + 5242880);   // 1MB  [B][T][H]
    float* y1f   = (float*)(ws + 6291456);   // 2MB  [B][T][H]
    float* qf    = (float*)(ws + 8388608);   // 2MB  [B][T][H]
    float* kT    = (float*)(ws + 10485760);  // 2MB  [B][H][T]
    u16*   nrm   = (u16*)  (ws + 14680064);  // 2MB  [B*T][512]
    u16*   Wqb   = (u16*)  (ws + 16908288);
    u16*   Wkb   = (u16*)  (ws + 17039360);
    u16*   Wfcb  = (u16*)  (ws + 17170432);  // 8MB

    float* hout = outp + (size_t)B_N * T_N * V_N;

    prep_all_kernel<<<4256, 256, 0, stream>>>(Wq, Wqb, Wk, Wkb, Wfc, Wfcb, Wih1, xfg);
    embed_xw0_kernel<<<512, 256, 0, stream>>>(x, emb, Wih0, bih0, bhh0, xw0);
    rnn_fused_kernel<<<1, 512, 0, stream>>>(Whh0, Whh1, xfg, bih1, bhh1,
                                            xw0, y1bf, y1f, hout);
    gemm_qk_kernel<<<256, 256, 0, stream>>>(y1bf, Wqb, Wkb, qf, kT);
    attn_ln_kernel<<<2048, 256, 0, stream>>>(qf, kT, y1f, vvec, gamma, beta, nrm);
    gemm_fc<<<16 * 64, 256, 0, stream>>>(nrm, Wfcb, bfc, outp);
}